// Round 1
// baseline (149.313 us; speedup 1.0000x reference)
//
#include <hip/hip_runtime.h>

#define CCH   256      // channels
#define HIDN  64       // hidden
#define GK    144      // groups * k*k
#define NB    8        // batch
#define NH    64
#define NW    64
#define NHW   4096     // 64*64
#define NG    16       // groups
#define CPG   16       // channels per group

// ---------------------------------------------------------------------------
// Kernel A: per-pixel kernel generation (two fused 1x1 convs + relu)
// block = 256 threads = 4 waves, handles 64 consecutive pixels (one image row)
// wave w computes hid[o] for o in [16w,16w+16) for all 64 pixels (lane=pixel),
// then Kmap[j] for j in [36w, 36w+36).
// Weight indices are wave-uniform -> scalar loads expected.
// ---------------------------------------------------------------------------
__global__ __launch_bounds__(256) void gen_kernel(
    const float* __restrict__ x,        // [B,256,64,64]
    const float* __restrict__ w_reduce, // [64,256]
    const float* __restrict__ b_reduce, // [64]
    const float* __restrict__ w_span,   // [144,64]
    const float* __restrict__ b_span,   // [144]
    float* __restrict__ kmap)           // [B,144,4096]
{
    __shared__ float hid_lds[64][65];   // [pixel][o], stride 65 -> <=2-way banks

    const int lane = threadIdx.x & 63;
    const int wid  = __builtin_amdgcn_readfirstlane(threadIdx.x >> 6);

    const int p0 = blockIdx.x * 64;     // first pixel of this block
    const int b  = p0 >> 12;            // / 4096 (blocks never span batch)
    const int hw = (p0 & 4095) + lane;

    const float* xb = x + (size_t)b * (CCH * NHW) + hw;

    // ---- phase 1: hid slice ----
    const int o0 = wid * 16;
    float acc[16];
    #pragma unroll
    for (int i = 0; i < 16; ++i) acc[i] = b_reduce[o0 + i];

    #pragma unroll 4
    for (int c = 0; c < CCH; ++c) {
        float xv = xb[c * NHW];                       // coalesced across lanes
        #pragma unroll
        for (int i = 0; i < 16; ++i)
            acc[i] = fmaf(w_reduce[(o0 + i) * CCH + c], xv, acc[i]);
    }
    #pragma unroll
    for (int i = 0; i < 16; ++i)
        hid_lds[lane][o0 + i] = fmaxf(acc[i], 0.0f);  // relu

    __syncthreads();

    // ---- phase 2: Kmap slice ----
    float h[64];
    #pragma unroll
    for (int o = 0; o < 64; ++o) h[o] = hid_lds[lane][o];

    float* kout = kmap + (size_t)b * (GK * NHW) + hw;
    const int j0 = wid * 36;
    for (int j = j0; j < j0 + 36; ++j) {
        float kacc = b_span[j];
        #pragma unroll
        for (int o = 0; o < 64; ++o)
            kacc = fmaf(w_span[j * HIDN + o], h[o], kacc);
        kout[j * NHW] = kacc;                          // coalesced across lanes
    }
}

// ---------------------------------------------------------------------------
// Kernel B: apply the involution.
// thread = (b, g, h, w); computes the 16 channels of its group.
// Border handling: clamp the tap address (always safe) and zero the
// corresponding kernel value -> branch-free inner loop.
// ---------------------------------------------------------------------------
__global__ __launch_bounds__(256) void apply_kernel(
    const float* __restrict__ x,     // [B,256,64,64]
    const float* __restrict__ kmap,  // [B,144,4096]
    float* __restrict__ out)         // [B,256,64,64]
{
    const int t  = blockIdx.x * 256 + threadIdx.x;   // [0, B*G*HW)
    const int hw = t & 4095;
    const int bg = t >> 12;
    const int g  = bg & 15;
    const int b  = bg >> 4;
    const int h  = hw >> 6;
    const int w  = hw & 63;

    // 9 kernel values for this (b,g,pixel)
    const float* kp = kmap + ((size_t)b * GK + g * 9) * NHW + hw;
    float kv[9];
    int   off[9];
    #pragma unroll
    for (int di = 0; di < 3; ++di) {
        const int hh  = h + di - 1;
        const int hcl = min(max(hh, 0), 63);
        const bool hv = (unsigned)hh < 64u;
        #pragma unroll
        for (int dj = 0; dj < 3; ++dj) {
            const int ww  = w + dj - 1;
            const int wcl = min(max(ww, 0), 63);
            const bool v  = hv && ((unsigned)ww < 64u);
            const int k   = di * 3 + dj;
            float kvv = kp[k * NHW];                  // coalesced across lanes
            kv[k]  = v ? kvv : 0.0f;                  // fold mask into kernel
            off[k] = (hcl - h) * 64 + (wcl - w);      // safe (clamped) tap
        }
    }

    const float* xp = x   + ((size_t)b * CCH + g * CPG) * NHW + hw;
    float*       op = out + ((size_t)b * CCH + g * CPG) * NHW + hw;

    #pragma unroll
    for (int n = 0; n < CPG; ++n) {
        float acc = 0.0f;
        #pragma unroll
        for (int k = 0; k < 9; ++k)
            acc = fmaf(xp[n * NHW + off[k]], kv[k], acc);
        op[n * NHW] = acc;
    }
}

// ---------------------------------------------------------------------------
extern "C" void kernel_launch(void* const* d_in, const int* in_sizes, int n_in,
                              void* d_out, int out_size, void* d_ws, size_t ws_size,
                              hipStream_t stream) {
    const float* x        = (const float*)d_in[0];
    const float* w_reduce = (const float*)d_in[1];
    const float* b_reduce = (const float*)d_in[2];
    const float* w_span   = (const float*)d_in[3];
    const float* b_span   = (const float*)d_in[4];
    float* out  = (float*)d_out;
    float* kmap = (float*)d_ws;   // needs B*144*4096*4 = 18.9 MB

    gen_kernel<<<dim3(NB * NHW / 64), dim3(256), 0, stream>>>(
        x, w_reduce, b_reduce, w_span, b_span, kmap);
    apply_kernel<<<dim3(NB * NG * NHW / 256), dim3(256), 0, stream>>>(
        x, kmap, out);
}